// Round 12
// baseline (110.498 us; speedup 1.0000x reference)
//
#include <hip/hip_runtime.h>
#include <hip/hip_fp16.h>

#define T_LEN 2048
#define NMODE 8
#define NPP   17   // 8 tau + 9 g (g[0]=g_infy)

typedef float floatx4 __attribute__((ext_vector_type(4)));

// ===========================================================================
// Phase A: block = 256 thr, G=8 chunks x L=16 steps (128 rows + 1 prev).
//  1) stage pp/t/Se (Se transposed [e][row]) into LDS, coalesced
//  2) row-parallel: 1/sum(g), g_infy/sum
//  3) row-parallel coeff pass: per (step,m) -> A,C into skewed LDS
//  4) concurrent, one branch per wave (no intra-wave branch serialization):
//     waves 0-1: scan thread = k*16+e (e<9), 8 modes in registers,
//                dS preloaded, 4x b128 prefetch per step;
//     wave 2   : S_infy plane writes;
//     wave 3   : (k,m) cumA mini-pass in LDS + partP.
//  5) bulk: qsum plane (float4), caA as packed fp16 (__half2).
// Outputs: S_infy plane (final), local-qsum plane (fixed by phaseC),
//          partR[b,e,c,m] f32, partP[b,c,m] f32, caA[b,c,s,m] fp16.
// ===========================================================================
template <int L, int G>
__global__ __launch_bounds__(256)
void phaseA(const float* __restrict__ Se,   // [B,T,3,3]
            const float* __restrict__ tt,   // [B,T]
            const float* __restrict__ pp,   // [B,T,17]
            float* __restrict__ out,        // [3,B,T,3,3]
            float* __restrict__ partR,      // [B,9,NC,8]
            float* __restrict__ partP,      // [B,NC,8]
            __half* __restrict__ caA,       // [B,NC,L,8] fp16
            int B) {
    constexpr int NC    = T_LEN / L;
    constexpr int NSTEP = G * L;          // 128
    constexpr int RW    = NSTEP + 1;      // 129
    constexpr int NT    = 256;
    constexpr int RAW_SZ = RW * NPP;               // 2193
    constexpr int QT_SZ  = 9 * (NSTEP + 4);        // 1188
    constexpr int CA_K   = L * 8 + 4;              // 132
    constexpr int UNION_SZ = (RAW_SZ > QT_SZ + G * CA_K) ? RAW_SZ
                                                         : (QT_SZ + G * CA_K);
    constexpr int AC_K  = L * 16 + 4;              // 260
    constexpr int O_AC  = UNION_SZ;
    constexpr int SROW  = NSTEP + 4;               // 132
    constexpr int O_ST  = O_AC + G * AC_K;
    constexpr int O_T   = O_ST + 9 * SROW;
    constexpr int O_INV = O_T + RW;
    constexpr int O_GI  = O_INV + RW;
    constexpr int TOTAL = O_GI + RW;

    __shared__ __align__(16) float sm[TOTAL];
    float* s_raw = sm;                    // union: raw inputs
    float* s_qT  = sm;                    // union: qsum transposed [e][t]
    float* s_ca  = sm + QT_SZ;            // union: cumA skewed [k][s][8] f32
    float* s_AC  = sm + O_AC;
    float* s_ST  = sm + O_ST;
    float* s_t   = sm + O_T;
    float* s_inv = sm + O_INV;
    float* s_gi  = sm + O_GI;

    const int tid  = threadIdx.x;
    const int ngrp = NC / G;
    const int b    = blockIdx.x / ngrp;
    const int grp  = blockIdx.x % ngrp;
    const int c0   = grp * G;
    const int base = c0 * L;
    const int off  = (base == 0) ? 0 : 1;
    const int r0   = (base == 0) ? 0 : base - 1;

    // ---- stage inputs ----
    {
        const float* pr = pp + ((size_t)b * T_LEN + r0) * NPP;
        for (int i = tid; i < RW * NPP; i += NT) s_raw[i] = pr[i];
        const float* sr = Se + ((size_t)b * T_LEN + r0) * 9;
        for (int i = tid; i < RW * 9; i += NT) {
            int r = i / 9, e = i - r * 9;
            s_ST[e * SROW + r] = sr[i];
        }
        const float* tr = tt + (size_t)b * T_LEN + r0;
        for (int i = tid; i < RW; i += NT) s_t[i] = tr[i];
    }
    __syncthreads();

    // ---- per-row 1/sum(g), g_infy/sum ----
    for (int i = tid; i < RW; i += NT) {
        float gs = 0.f;
        #pragma unroll
        for (int k = 8; k < NPP; ++k) gs += s_raw[i * NPP + k];
        float iv = __builtin_amdgcn_rcpf(gs);
        s_inv[i] = iv;
        s_gi[i]  = s_raw[i * NPP + 8] * iv;
    }
    __syncthreads();

    // ---- per-(step,mode) coefficients: all exp/rcp here ----
    for (int i = tid; i < NSTEP * 8; i += NT) {
        int m  = i & 7;
        int ts = i >> 3;
        int rc = ts + off;
        bool first = (base == 0) && (ts == 0);
        int rp = first ? rc : rc - 1;
        float tau_c = s_raw[rc * NPP + m];
        float tau_p = s_raw[rp * NPP + m];
        float gqh_c = 0.5f * s_raw[rc * NPP + 9 + m] * s_inv[rc];
        float gqh_p = 0.5f * s_raw[rp * NPP + 9 + m] * s_inv[rp];
        float t_c = s_t[rc];
        float t_p = first ? -s_t[1] : s_t[rp];
        float ee  = __expf((t_p - t_c) * __builtin_amdgcn_rcpf(tau_c + tau_p));
        int kk = ts / L, sl = ts % L;
        s_AC[kk * AC_K + sl * 16 + m]     = ee * ee;              // A
        s_AC[kk * AC_K + sl * 16 + 8 + m] = ee * (gqh_c + gqh_p); // C
    }
    __syncthreads();   // s_raw consumed; union becomes s_qT/s_ca

    const size_t nOut = (size_t)B * T_LEN * 9;

    if (tid < 128) {
        // ---- waves 0-1: scan thread (k = tid/16, e = tid%16 < 9) ----
        const int k = tid >> 4;
        const int e = tid & 15;
        if (e < 9) {
            const int cg = c0 + k;
            float dS[L];
            {
                float Sv[L + 1];
                Sv[0] = (cg == 0) ? 0.f : s_ST[e * SROW + (k * L + off - 1)];
                #pragma unroll
                for (int s = 0; s < L; ++s)
                    Sv[s + 1] = s_ST[e * SROW + (k * L + s + off)];
                #pragma unroll
                for (int s = 0; s < L; ++s) dS[s] = Sv[s + 1] - Sv[s];
            }

            float Q[8] = {0,0,0,0,0,0,0,0};
            const float4* acp = (const float4*)(s_AC + k * AC_K);

            float4 a0 = acp[0], a1 = acp[1], c0v = acp[2], c1v = acp[3];
            #pragma unroll
            for (int s = 0; s < L; ++s) {
                float4 na0, na1, nc0, nc1;
                if (s < L - 1) {
                    na0 = acp[4*s+4]; na1 = acp[4*s+5];
                    nc0 = acp[4*s+6]; nc1 = acp[4*s+7];
                }
                float d = dS[s];
                Q[0] = a0.x*Q[0] + c0v.x*d;  Q[1] = a0.y*Q[1] + c0v.y*d;
                Q[2] = a0.z*Q[2] + c0v.z*d;  Q[3] = a0.w*Q[3] + c0v.w*d;
                Q[4] = a1.x*Q[4] + c1v.x*d;  Q[5] = a1.y*Q[5] + c1v.y*d;
                Q[6] = a1.z*Q[6] + c1v.z*d;  Q[7] = a1.w*Q[7] + c1v.w*d;
                float qs = ((Q[0]+Q[1])+(Q[2]+Q[3])) + ((Q[4]+Q[5])+(Q[6]+Q[7]));
                s_qT[e * SROW + (k * L + s)] = qs;
                a0 = na0; a1 = na1; c0v = nc0; c1v = nc1;
            }

            float4* pr4 = (float4*)(partR + ((size_t)(b * 9 + e) * NC + cg) * 8);
            pr4[0] = make_float4(Q[0], Q[1], Q[2], Q[3]);
            pr4[1] = make_float4(Q[4], Q[5], Q[6], Q[7]);
        }
    } else if (tid < 192) {
        // ---- wave 2: S_infy plane ----
        float* o1 = out + nOut + ((size_t)b * T_LEN + base) * 9;
        for (int i = tid - 128; i < NSTEP * 9; i += 64) {
            int t = i / 9, e = i - t * 9;
            int rc = t + off;
            o1[i] = s_gi[rc] * s_ST[e * SROW + rc];
        }
    } else {
        // ---- wave 3 = (k,m): cumA mini-pass + partP ----
        const int u = tid - 192;
        const int k = u >> 3;
        const int m = u & 7;
        float c = 1.f;
        #pragma unroll
        for (int s = 0; s < L; ++s) {
            c *= s_AC[k * AC_K + s * 16 + m];
            s_ca[k * CA_K + s * 8 + m] = c;
        }
        partP[((size_t)b * NC + (c0 + k)) * 8 + m] = c;
    }
    __syncthreads();

    // ---- bulk coalesced writes: local-qsum plane (f4) + caA (fp16x2) ----
    float* o2 = out + 2 * nOut + ((size_t)b * T_LEN + base) * 9;
    for (int i4 = tid; i4 < NSTEP * 9 / 4; i4 += NT) {
        int i = i4 * 4;
        float4 v;
        {
            int t0i = i / 9,     e0i = i - t0i * 9;
            int t1i = (i+1) / 9, e1i = (i+1) - t1i * 9;
            int t2i = (i+2) / 9, e2i = (i+2) - t2i * 9;
            int t3i = (i+3) / 9, e3i = (i+3) - t3i * 9;
            v.x = s_qT[e0i * SROW + t0i];
            v.y = s_qT[e1i * SROW + t1i];
            v.z = s_qT[e2i * SROW + t2i];
            v.w = s_qT[e3i * SROW + t3i];
        }
        ((float4*)o2)[i4] = v;
    }
    {
        __half2* ca2 = (__half2*)(caA + ((size_t)b * NC + c0) * (L * 8));
        for (int j = tid; j < G * L * 8 / 2; j += NT) {
            int h = 2 * j;
            int k = h >> 7;              // / (L*8)
            int r = h & 127;
            int s = r >> 3, m = r & 7;   // m even
            float va = s_ca[k * CA_K + s * 8 + m];
            float vb = s_ca[k * CA_K + s * 8 + m + 1];
            ca2[j] = __float22half2_rn(make_float2(va, vb));
        }
    }
}

// ===========================================================================
// Phase B: inter-chunk scan, ONE WAVE per (b,e) (proven R4/R7-R10). Converts
// partR in place from local chunk results to entering states Z (exclusive).
// ===========================================================================
template <int K>
__global__ __launch_bounds__(256)
void chunk_scan_wave(float* __restrict__ R, const float* __restrict__ P,
                     int B) {
    constexpr int NC = K * 64;
    int gtid = blockIdx.x * blockDim.x + threadIdx.x;
    int wid  = gtid >> 6;
    int lane = gtid & 63;
    if (wid >= B * 9) return;
    int e = wid % 9;
    int b = wid / 9;

    float* rp       = R + ((size_t)(b * 9 + e) * NC) * NMODE;
    const float* pq = P + ((size_t)b * NC) * NMODE;

    float pk[K][NMODE], rk[K][NMODE];
    float pa[NMODE], ra[NMODE];
    #pragma unroll
    for (int m = 0; m < NMODE; ++m) { pa[m] = 1.f; ra[m] = 0.f; }

    #pragma unroll
    for (int k = 0; k < K; ++k) {
        int c = lane * K + k;
        const float4* rv = (const float4*)(rp + (size_t)c * NMODE);
        const float4* pv = (const float4*)(pq + (size_t)c * NMODE);
        float4 r0 = rv[0], r1 = rv[1], p0 = pv[0], p1 = pv[1];
        rk[k][0]=r0.x; rk[k][1]=r0.y; rk[k][2]=r0.z; rk[k][3]=r0.w;
        rk[k][4]=r1.x; rk[k][5]=r1.y; rk[k][6]=r1.z; rk[k][7]=r1.w;
        pk[k][0]=p0.x; pk[k][1]=p0.y; pk[k][2]=p0.z; pk[k][3]=p0.w;
        pk[k][4]=p1.x; pk[k][5]=p1.y; pk[k][6]=p1.z; pk[k][7]=p1.w;
        #pragma unroll
        for (int m = 0; m < NMODE; ++m) {
            ra[m] = pk[k][m] * ra[m] + rk[k][m];
            pa[m] = pk[k][m] * pa[m];
        }
    }

    #pragma unroll
    for (int d = 1; d < 64; d <<= 1) {
        #pragma unroll
        for (int m = 0; m < NMODE; ++m) {
            float plo = __shfl_up(pa[m], d);
            float rlo = __shfl_up(ra[m], d);
            if (lane >= d) {
                ra[m] = pa[m] * rlo + ra[m];
                pa[m] = pa[m] * plo;
            }
        }
    }

    float z[NMODE];
    #pragma unroll
    for (int m = 0; m < NMODE; ++m) {
        float zz = __shfl_up(ra[m], 1);
        z[m] = (lane == 0) ? 0.f : zz;
    }

    #pragma unroll
    for (int k = 0; k < K; ++k) {
        int c = lane * K + k;
        float4* rv = (float4*)(rp + (size_t)c * NMODE);
        rv[0] = make_float4(z[0], z[1], z[2], z[3]);
        rv[1] = make_float4(z[4], z[5], z[6], z[7]);
        #pragma unroll
        for (int m = 0; m < NMODE; ++m)
            z[m] = pk[k][m] * z[m] + rk[k][m];
    }
}

// ===========================================================================
// Phase C: 256-thread block per GC chunks, float4 plane traffic, fp16 caA,
// nontemporal final stores. corr_t[e] = sum_m caA[t,m]*Z[e,m].
// ===========================================================================
template <int L, int GC>
__global__ __launch_bounds__(256)
void phaseC(float* __restrict__ out,
            const float* __restrict__ partR,   // now Z [b,9,NC,8]
            const __half* __restrict__ caA,    // [B,NC,L,8] fp16
            int B) {
    constexpr int NC = T_LEN / L;
    constexpr int NE = GC * L * 9;
    const int tid  = threadIdx.x;
    const int ngrp = NC / GC;
    const int b  = blockIdx.x / ngrp;
    const int g  = blockIdx.x % ngrp;
    const int c0 = g * GC;

    __shared__ float s_Z[GC * 72];
    __shared__ __align__(16) float s_ca[GC * L * 8];

    for (int i = tid; i < GC * 72; i += 256) {
        int cl = i / 72, u = i % 72, e = u >> 3, m = u & 7;
        s_Z[i] = partR[((size_t)(b * 9 + e) * NC + c0 + cl) * 8 + m];
    }
    {
        const __half2* ca2 = (const __half2*)(caA + ((size_t)b * NC + c0) * (L * 8));
        for (int i = tid; i < GC * L * 4; i += 256) {
            float2 v = __half22float2(ca2[i]);
            s_ca[2 * i]     = v.x;
            s_ca[2 * i + 1] = v.y;
        }
    }
    __syncthreads();

    const size_t nOut = (size_t)B * T_LEN * 9;
    float* o = out + ((size_t)b * T_LEN + (size_t)c0 * L) * 9;
    const float4* sf4 = (const float4*)(o + nOut);
    floatx4* s4 = (floatx4*)o;
    floatx4* q4 = (floatx4*)(o + 2 * nOut);

    for (int i4 = tid; i4 < NE / 4; i4 += 256) {
        int i = i4 * 4;
        floatx4 qv = q4[i4];
        float4 fv = sf4[i4];
        float corr[4];
        #pragma unroll
        for (int j = 0; j < 4; ++j) {
            int t = (i + j) / 9, e = (i + j) - t * 9;
            int cl = t / L;
            const float* caT = &s_ca[t * 8];
            const float* zE  = &s_Z[cl * 72 + e * 8];
            float cr = 0.f;
            #pragma unroll
            for (int m = 0; m < NMODE; ++m) cr += caT[m] * zE[m];
            corr[j] = cr;
        }
        floatx4 qn;
        qn.x = qv.x + corr[0]; qn.y = qv.y + corr[1];
        qn.z = qv.z + corr[2]; qn.w = qv.w + corr[3];
        floatx4 sn;
        sn.x = fv.x + qn.x; sn.y = fv.y + qn.y;
        sn.z = fv.z + qn.z; sn.w = fv.w + qn.w;
        __builtin_nontemporal_store(qn, &q4[i4]);
        __builtin_nontemporal_store(sn, &s4[i4]);
    }
}

// ===========================================================================
extern "C" void kernel_launch(void* const* d_in, const int* in_sizes, int n_in,
                              void* d_out, int out_size, void* d_ws, size_t ws_size,
                              hipStream_t stream) {
    const float* Se = (const float*)d_in[0];
    const float* tt = (const float*)d_in[1];
    const float* pp = (const float*)d_in[2];
    float* out = (float*)d_out;

    int B = in_sizes[1] / T_LEN;

    constexpr int L  = 16;
    constexpr int NC = T_LEN / L;     // 128
    constexpr int K  = NC / 64;       // 2
    constexpr int G  = 8;             // chunks per phaseA block
    constexpr int GC = 8;             // chunks per phaseC block

    float*  partR = (float*)d_ws;                                 // B*9*NC*8 f32
    float*  partP = partR + (size_t)B * 9 * NC * 8;               // B*NC*8 f32
    __half* caA   = (__half*)(partP + (size_t)B * NC * 8);        // B*NC*L*8 fp16

    int gridA = B * (NC / G);
    int gridB = (B * 9 * 64 + 255) / 256;
    int gridC = B * (NC / GC);

    phaseA<L, G><<<gridA, dim3(256), 0, stream>>>(
        Se, tt, pp, out, partR, partP, caA, B);
    chunk_scan_wave<K><<<gridB, dim3(256), 0, stream>>>(partR, partP, B);
    phaseC<L, GC><<<gridC, dim3(256), 0, stream>>>(out, partR, caA, B);
}